// Round 1
// baseline (306.635 us; speedup 1.0000x reference)
//
#include <hip/hip_runtime.h>
#include <hip/hip_bf16.h>
#include <stdint.h>

typedef unsigned int u32;
typedef __attribute__((ext_vector_type(8))) short short8;   // 8 bf16 = 4 VGPRs (MFMA A/B frag)
typedef __attribute__((ext_vector_type(4))) float floatx4;  // MFMA C/D frag

// Problem constants
#define N_BIT 4
#define N_ROW 8
#define N_COL 8
#define YROW 128
#define ZCOL 128
#define K8 32            // packed bytes per k-row (K=256)
#define M_DIM 16384      // BATCH*SEQ
#define N_DIM 1024       // ROW*Y_ROW (output features)
#define K_DIM 1024       // COL*Z_COL (input features)

// ---------------------------------------------------------------------------
// Kernel 0: detect whether packed tensors arrived as uint8 (mode 0) or were
// widened to int32 by the harness (mode 1). Exact check: popcount of the
// first 32 bytes must equal Y_sum[0] under the uint8 interpretation.
// ---------------------------------------------------------------------------
__global__ void detect_mode(const uint8_t* __restrict__ yp,
                            const int* __restrict__ ysum,
                            u32* __restrict__ flag) {
    if (threadIdx.x == 0) {
        int s = 0;
        for (int t = 0; t < K8; ++t) s += __popc((u32)yp[t]);
        flag[0] = (s == ysum[0]) ? 0u : 1u;
    }
}

// ---------------------------------------------------------------------------
// Kernel 1: canonicalize Y_packed/Z_packed to uint8 in workspace.
// 65536 uint4 chunks per tensor (1 MiB each).
// ---------------------------------------------------------------------------
__global__ __launch_bounds__(256) void normalize_packed(
        const u32* __restrict__ ysrc, const u32* __restrict__ zsrc,
        uint8_t* __restrict__ ydst, uint8_t* __restrict__ zdst,
        const u32* __restrict__ flag) {
    const int i = blockIdx.x * 256 + threadIdx.x;  // uint4 chunk id
    if (*flag == 0) {
        ((uint4*)ydst)[i] = ((const uint4*)ysrc)[i];
        ((uint4*)zdst)[i] = ((const uint4*)zsrc)[i];
    } else {
        uint4 ya[4], za[4];
#pragma unroll
        for (int j = 0; j < 4; ++j) {
            ya[j] = ((const uint4*)ysrc)[i * 4 + j];
            za[j] = ((const uint4*)zsrc)[i * 4 + j];
        }
        uint4 yo, zo;
        yo.x = (ya[0].x & 0xff) | ((ya[0].y & 0xff) << 8) | ((ya[0].z & 0xff) << 16) | (ya[0].w << 24);
        yo.y = (ya[1].x & 0xff) | ((ya[1].y & 0xff) << 8) | ((ya[1].z & 0xff) << 16) | (ya[1].w << 24);
        yo.z = (ya[2].x & 0xff) | ((ya[2].y & 0xff) << 8) | ((ya[2].z & 0xff) << 16) | (ya[2].w << 24);
        yo.w = (ya[3].x & 0xff) | ((ya[3].y & 0xff) << 8) | ((ya[3].z & 0xff) << 16) | (ya[3].w << 24);
        zo.x = (za[0].x & 0xff) | ((za[0].y & 0xff) << 8) | ((za[0].z & 0xff) << 16) | (za[0].w << 24);
        zo.y = (za[1].x & 0xff) | ((za[1].y & 0xff) << 8) | ((za[1].z & 0xff) << 16) | (za[1].w << 24);
        zo.z = (za[2].x & 0xff) | ((za[2].y & 0xff) << 8) | ((za[2].z & 0xff) << 16) | (za[2].w << 24);
        zo.w = (za[3].x & 0xff) | ((za[3].y & 0xff) << 8) | ((za[3].z & 0xff) << 16) | (za[3].w << 24);
        ((uint4*)ydst)[i] = yo;
        ((uint4*)zdst)[i] = zo;
    }
}

// ---------------------------------------------------------------------------
// Kernel 2: build W (bf16, row-major [N_DIM][K_DIM], m=r*128+y, k=c*128+z).
// W[m,k] = d + sum_bit( a[bit]*popcnt(Y&Z) + b[bit]*Ysum + c[bit]*Zsum )
// Grid: 256 blocks = (r,c) x z-quarter. 256 threads.
// ---------------------------------------------------------------------------
__global__ __launch_bounds__(256) void build_w(
        const uint8_t* __restrict__ yp, const uint8_t* __restrict__ zp,
        const int* __restrict__ ysum, const int* __restrict__ zsum,
        const float* __restrict__ pa, const float* __restrict__ pb,
        const float* __restrict__ pc, const float* __restrict__ pd,
        __hip_bfloat16* __restrict__ Wb) {
    __shared__ u32 sY[N_BIT * YROW * 8];   // [bit][y][t/4] words, 16 KiB
    __shared__ u32 sZ[N_BIT * 32 * 8];     // [bit][zl][t/4] words, 4 KiB
    __shared__ int sYs[N_BIT * YROW];
    __shared__ int sZs[N_BIT * 32];

    const int tid = threadIdx.x;
    const int rc = blockIdx.x >> 2;
    const int zq = blockIdx.x & 3;
    const int r = rc >> 3, c = rc & 7;
    const int z0 = zq * 32;

    // Stage Y words: flat f = bit*1024 + y*8 + t  (4096 words)
#pragma unroll
    for (int j = 0; j < 4; ++j) {
        const int chunk = tid + j * 256;          // uint4 chunk
        const int f = chunk * 4;
        const int bit = f >> 10, rem = f & 1023;
        const u32 gword = (u32)(((bit * 8 + r) * 8 + c) * 1024 + rem);
        ((uint4*)sY)[chunk] = *(const uint4*)(yp + (size_t)gword * 4);
    }
    // Stage Z quarter: flat f = bit*256 + zl*8 + t (1024 words)
    {
        const int f = tid * 4;
        const int bit = f >> 8, rem = f & 255;
        const int zl = rem >> 3, t = rem & 7;
        const u32 gword = (u32)(((bit * 8 + r) * 8 + c) * 1024 + (z0 + zl) * 8 + t);
        ((uint4*)sZ)[tid] = *(const uint4*)(zp + (size_t)gword * 4);
    }
    // Stage sums
    for (int j = tid; j < N_BIT * YROW; j += 256) {
        const int bit = j >> 7, y = j & 127;
        sYs[j] = ysum[((bit * 8 + r) * 8 + c) * 128 + y];
    }
    if (tid < N_BIT * 32) {
        const int bit = tid >> 5, zl = tid & 31;
        sZs[tid] = zsum[((bit * 8 + r) * 8 + c) * 128 + z0 + zl];
    }
    __syncthreads();

    float av[4], bv[4], cv[4];
#pragma unroll
    for (int bit = 0; bit < 4; ++bit) { av[bit] = pa[bit]; bv[bit] = pb[bit]; cv[bit] = pc[bit]; }
    const float dv = pd[0];

    const int y = tid & 127;
    const int zh = tid >> 7;       // 0/1 -> 16 z each

    u32 yw[4][8];
    float base = dv;
#pragma unroll
    for (int bit = 0; bit < 4; ++bit) {
        const uint4 q0 = ((const uint4*)sY)[bit * 256 + y * 2];
        const uint4 q1 = ((const uint4*)sY)[bit * 256 + y * 2 + 1];
        yw[bit][0] = q0.x; yw[bit][1] = q0.y; yw[bit][2] = q0.z; yw[bit][3] = q0.w;
        yw[bit][4] = q1.x; yw[bit][5] = q1.y; yw[bit][6] = q1.z; yw[bit][7] = q1.w;
        base += bv[bit] * (float)sYs[bit * 128 + y];
    }

    const int m = r * 128 + y;
#pragma unroll
    for (int zl2 = 0; zl2 < 16; ++zl2) {
        const int zl = zh * 16 + zl2;
        float wv = base;
#pragma unroll
        for (int bit = 0; bit < 4; ++bit) {
            const uint4 zw0 = ((const uint4*)sZ)[bit * 64 + zl * 2];
            const uint4 zw1 = ((const uint4*)sZ)[bit * 64 + zl * 2 + 1];
            int p = 0;
            p += __popc(yw[bit][0] & zw0.x);
            p += __popc(yw[bit][1] & zw0.y);
            p += __popc(yw[bit][2] & zw0.z);
            p += __popc(yw[bit][3] & zw0.w);
            p += __popc(yw[bit][4] & zw1.x);
            p += __popc(yw[bit][5] & zw1.y);
            p += __popc(yw[bit][6] & zw1.z);
            p += __popc(yw[bit][7] & zw1.w);
            wv += av[bit] * (float)p + cv[bit] * (float)sZs[bit * 32 + zl];
        }
        const int k = c * 128 + z0 + zl;
        Wb[(size_t)m * K_DIM + k] = __float2bfloat16(wv);
    }
}

// ---------------------------------------------------------------------------
// Kernel 3: out[M,N] = Xf[M,K] * Wb[N,K]^T + bias[N]   (bf16 MFMA, fp32 out)
// 128x128 tile, BK=64, 256 threads = 2x2 waves of 64x64.
// A staging fuses fp32->bf16 (v_perm truncation). LDS row stride 36 u32
// (144 B) -> conflict-free ds_read_b128 fragments.
// ---------------------------------------------------------------------------
#define LDSW 36   // u32 per LDS row (64 bf16 = 32 u32, +4 pad)

__global__ __launch_bounds__(256) void gemm_bias(
        const float* __restrict__ X, const u32* __restrict__ Wb,
        const float* __restrict__ bias, float* __restrict__ out) {
    __shared__ u32 As[128 * LDSW];   // 18 KiB
    __shared__ u32 Bs[128 * LDSW];   // 18 KiB

    const int tid = threadIdx.x;
    const int lane = tid & 63;
    const int wave = tid >> 6;
    const int wr = wave >> 1, wc = wave & 1;
    const int ntile = blockIdx.x;    // 0..7
    const int mtile = blockIdx.y;    // 0..127

    // Staging: thread -> (row = tid>>1, half = tid&1) covering 32 cols each
    const int srow = tid >> 1;
    const int shalf = tid & 1;
    const float* aptr = X + (size_t)(mtile * 128 + srow) * K_DIM + shalf * 32;
    const u32*   bptr = Wb + ((size_t)(ntile * 128 + srow) * K_DIM + shalf * 32) / 2;
    u32* aw = As + srow * LDSW + shalf * 16;
    u32* bw = Bs + srow * LDSW + shalf * 16;

    // Fragment read lanes
    const int fm = lane & 15;
    const int fq = lane >> 4;

    floatx4 acc[4][4] = {};

    float4 av4[8];
    uint4  bv4[4];
    // preload k-tile 0
#pragma unroll
    for (int j = 0; j < 8; ++j) av4[j] = ((const float4*)aptr)[j];
#pragma unroll
    for (int j = 0; j < 4; ++j) bv4[j] = ((const uint4*)bptr)[j];

    for (int kt = 0; kt < K_DIM / 64; ++kt) {
        __syncthreads();   // previous tile's readers done
        // write A (fp32 -> bf16 truncate via v_perm) and B to LDS
#pragma unroll
        for (int j = 0; j < 4; ++j) {
            const u32* f = (const u32*)&av4[j * 2];
            const u32* g = (const u32*)&av4[j * 2 + 1];
            uint4 w;
            w.x = __builtin_amdgcn_perm(f[1], f[0], 0x07060302u);
            w.y = __builtin_amdgcn_perm(f[3], f[2], 0x07060302u);
            w.z = __builtin_amdgcn_perm(g[1], g[0], 0x07060302u);
            w.w = __builtin_amdgcn_perm(g[3], g[2], 0x07060302u);
            *(uint4*)(aw + j * 4) = w;
        }
#pragma unroll
        for (int j = 0; j < 4; ++j) *(uint4*)(bw + j * 4) = bv4[j];
        __syncthreads();

        // prefetch next k-tile while computing this one
        if (kt + 1 < K_DIM / 64) {
            const int k0 = (kt + 1) * 64;
#pragma unroll
            for (int j = 0; j < 8; ++j) av4[j] = ((const float4*)(aptr + k0))[j];
#pragma unroll
            for (int j = 0; j < 4; ++j) bv4[j] = ((const uint4*)(bptr + k0 / 2))[j];
        }

#pragma unroll
        for (int kk = 0; kk < 2; ++kk) {
            short8 afr[4], bfr[4];
#pragma unroll
            for (int mi = 0; mi < 4; ++mi) {
                const int row = wr * 64 + mi * 16 + fm;
                afr[mi] = *(const short8*)(As + row * LDSW + kk * 16 + fq * 4);
            }
#pragma unroll
            for (int ni = 0; ni < 4; ++ni) {
                const int row = wc * 64 + ni * 16 + fm;
                bfr[ni] = *(const short8*)(Bs + row * LDSW + kk * 16 + fq * 4);
            }
#pragma unroll
            for (int mi = 0; mi < 4; ++mi)
#pragma unroll
                for (int ni = 0; ni < 4; ++ni)
                    acc[mi][ni] = __builtin_amdgcn_mfma_f32_16x16x32_bf16(
                        afr[mi], bfr[ni], acc[mi][ni], 0, 0, 0);
        }
    }

    // Epilogue: D layout col=lane&15, row=(lane>>4)*4+reg
    float bias_r[4];
#pragma unroll
    for (int ni = 0; ni < 4; ++ni)
        bias_r[ni] = bias[ntile * 128 + wc * 64 + ni * 16 + fm];
#pragma unroll
    for (int mi = 0; mi < 4; ++mi) {
#pragma unroll
        for (int reg = 0; reg < 4; ++reg) {
            const int row = mtile * 128 + wr * 64 + mi * 16 + fq * 4 + reg;
            float* orow = out + (size_t)row * N_DIM + ntile * 128 + wc * 64 + fm;
#pragma unroll
            for (int ni = 0; ni < 4; ++ni)
                orow[ni * 16] = acc[mi][ni][reg] + bias_r[ni];
        }
    }
}

// ---------------------------------------------------------------------------
extern "C" void kernel_launch(void* const* d_in, const int* in_sizes, int n_in,
                              void* d_out, int out_size, void* d_ws, size_t ws_size,
                              hipStream_t stream) {
    const float* X   = (const float*)d_in[0];
    const void*  Yp  = d_in[1];
    const void*  Zp  = d_in[2];
    const int*   Ys  = (const int*)d_in[3];
    const int*   Zs  = (const int*)d_in[4];
    const float* pa  = (const float*)d_in[5];
    const float* pb  = (const float*)d_in[6];
    const float* pc  = (const float*)d_in[7];
    const float* pd  = (const float*)d_in[8];
    const float* bias = (const float*)d_in[9];
    float* out = (float*)d_out;

    char* ws = (char*)d_ws;
    u32* flag = (u32*)ws;
    uint8_t* Yn = (uint8_t*)(ws + 4096);
    uint8_t* Zn = (uint8_t*)(ws + 4096 + (1 << 20));
    __hip_bfloat16* Wb = (__hip_bfloat16*)(ws + 4096 + (2 << 20));

    detect_mode<<<1, 64, 0, stream>>>((const uint8_t*)Yp, Ys, flag);
    normalize_packed<<<256, 256, 0, stream>>>((const u32*)Yp, (const u32*)Zp, Yn, Zn, flag);
    build_w<<<256, 256, 0, stream>>>(Yn, Zn, Ys, Zs, pa, pb, pc, pd, Wb);
    gemm_bias<<<dim3(8, 128), 256, 0, stream>>>(X, (const u32*)Wb, bias, out);
}

// Round 2
// 286.083 us; speedup vs baseline: 1.0718x; 1.0718x over previous
//
#include <hip/hip_runtime.h>
#include <hip/hip_bf16.h>
#include <stdint.h>

typedef unsigned int u32;
typedef __attribute__((ext_vector_type(8))) short short8;   // 8 bf16 = 4 VGPRs (MFMA A/B frag)
typedef __attribute__((ext_vector_type(4))) float floatx4;  // MFMA C/D frag

#define N_DIM 1024       // ROW*Y_ROW (output features)
#define K_DIM 1024       // COL*Z_COL (input features)
#define LDSW 36          // main-loop LDS row stride in u32 (64 bf16 = 32 words, +4 pad)
#define EPW  68          // epilogue LDS row stride in words (64 fp32 + 4 pad -> 2-way-free)

__device__ __forceinline__ u32 pack4(uint4 v) {
    return (v.x & 0xffu) | ((v.y & 0xffu) << 8) | ((v.z & 0xffu) << 16) | (v.w << 24);
}

// ---------------------------------------------------------------------------
// build_w: W[m,k] (bf16, row-major [N_DIM][K_DIM], m=r*128+y, k=c*128+z)
//   = d + sum_bit( a*popcnt(Y&Z) + b*Ysum + c*Zsum )
// Mode detection folded in: every block/thread checks (uniformly) whether the
// packed tensors arrived as raw uint8 or int32-widened (popc of first 32
// logical bytes must equal Y_sum[0] under the uint8 interpretation).
// Grid: 256 blocks = (r,c) x z-quarter, 256 threads.
// ---------------------------------------------------------------------------
__global__ __launch_bounds__(256) void build_w(
        const u32* __restrict__ yp, const u32* __restrict__ zp,
        const int* __restrict__ ysum, const int* __restrict__ zsum,
        const float* __restrict__ pa, const float* __restrict__ pb,
        const float* __restrict__ pc, const float* __restrict__ pd,
        __hip_bfloat16* __restrict__ Wb) {
    __shared__ u32 sY[4096];   // [bit][y][t] words (16 KiB)
    __shared__ u32 sZ[1024];   // [bit][zl][t] words (4 KiB)
    __shared__ int sYs[512];
    __shared__ int sZs[128];

    const int tid = threadIdx.x;
    const int rc = blockIdx.x >> 2;
    const int zq = blockIdx.x & 3;
    const int r = rc >> 3, c = rc & 7;
    const int z0 = zq * 32;

    // uniform mode detect (32 logical bytes vs Y_sum[0])
    const uint4 d0 = ((const uint4*)yp)[0], d1 = ((const uint4*)yp)[1];
    const int sdet = __popc(d0.x) + __popc(d0.y) + __popc(d0.z) + __popc(d0.w)
                   + __popc(d1.x) + __popc(d1.y) + __popc(d1.z) + __popc(d1.w);
    const bool widened = (sdet != ysum[0]);

    if (!widened) {
#pragma unroll
        for (int j = 0; j < 4; ++j) {
            const int chunk = tid + j * 256;
            const int f = chunk * 4;                    // logical word id in block
            const int bit = f >> 10, rem = f & 1023;
            const u32 gw = (u32)((bit * 64 + r * 8 + c) * 1024 + rem);
            ((uint4*)sY)[chunk] = *(const uint4*)(yp + gw);
        }
        {
            const int f = tid * 4;
            const int bit = f >> 8;
            const u32 gw = (u32)((bit * 64 + r * 8 + c) * 1024 + z0 * 8 + (f & 255));
            ((uint4*)sZ)[tid] = *(const uint4*)(zp + gw);
        }
    } else {
        // int32-widened: logical word w = pack of uint4 at index w
#pragma unroll
        for (int j = 0; j < 4; ++j) {
            const int chunk = tid + j * 256;
            const int f = chunk * 4;
            const int bit = f >> 10, rem = f & 1023;
            const u32 gw = (u32)((bit * 64 + r * 8 + c) * 1024 + rem);
            uint4 o;
            o.x = pack4(((const uint4*)yp)[gw + 0]);
            o.y = pack4(((const uint4*)yp)[gw + 1]);
            o.z = pack4(((const uint4*)yp)[gw + 2]);
            o.w = pack4(((const uint4*)yp)[gw + 3]);
            ((uint4*)sY)[chunk] = o;
        }
        {
            const int f = tid * 4;
            const int bit = f >> 8;
            const u32 gw = (u32)((bit * 64 + r * 8 + c) * 1024 + z0 * 8 + (f & 255));
            uint4 o;
            o.x = pack4(((const uint4*)zp)[gw + 0]);
            o.y = pack4(((const uint4*)zp)[gw + 1]);
            o.z = pack4(((const uint4*)zp)[gw + 2]);
            o.w = pack4(((const uint4*)zp)[gw + 3]);
            ((uint4*)sZ)[tid] = o;
        }
    }
    // sums
    for (int j = tid; j < 512; j += 256) {
        const int bit = j >> 7, y = j & 127;
        sYs[j] = ysum[((bit * 8 + r) * 8 + c) * 128 + y];
    }
    if (tid < 128) {
        const int bit = tid >> 5, zl = tid & 31;
        sZs[tid] = zsum[((bit * 8 + r) * 8 + c) * 128 + z0 + zl];
    }
    __syncthreads();

    float av[4], bv[4], cv[4];
#pragma unroll
    for (int bit = 0; bit < 4; ++bit) { av[bit] = pa[bit]; bv[bit] = pb[bit]; cv[bit] = pc[bit]; }
    const float dv = pd[0];

    const int y = tid & 127;
    const int zh = tid >> 7;       // 0/1 -> 16 z each

    u32 yw[4][8];
    float base = dv;
#pragma unroll
    for (int bit = 0; bit < 4; ++bit) {
        const uint4 q0 = ((const uint4*)sY)[bit * 256 + y * 2];
        const uint4 q1 = ((const uint4*)sY)[bit * 256 + y * 2 + 1];
        yw[bit][0] = q0.x; yw[bit][1] = q0.y; yw[bit][2] = q0.z; yw[bit][3] = q0.w;
        yw[bit][4] = q1.x; yw[bit][5] = q1.y; yw[bit][6] = q1.z; yw[bit][7] = q1.w;
        base += bv[bit] * (float)sYs[bit * 128 + y];
    }

    const int m = r * 128 + y;
#pragma unroll
    for (int zl2 = 0; zl2 < 16; ++zl2) {
        const int zl = zh * 16 + zl2;
        float wv = base;
#pragma unroll
        for (int bit = 0; bit < 4; ++bit) {
            const uint4 zw0 = ((const uint4*)sZ)[bit * 64 + zl * 2];
            const uint4 zw1 = ((const uint4*)sZ)[bit * 64 + zl * 2 + 1];
            int p = 0;
            p += __popc(yw[bit][0] & zw0.x);
            p += __popc(yw[bit][1] & zw0.y);
            p += __popc(yw[bit][2] & zw0.z);
            p += __popc(yw[bit][3] & zw0.w);
            p += __popc(yw[bit][4] & zw1.x);
            p += __popc(yw[bit][5] & zw1.y);
            p += __popc(yw[bit][6] & zw1.z);
            p += __popc(yw[bit][7] & zw1.w);
            wv += av[bit] * (float)p + cv[bit] * (float)sZs[bit * 32 + zl];
        }
        const int k = c * 128 + z0 + zl;
        Wb[(size_t)m * K_DIM + k] = __float2bfloat16(wv);
    }
}

// ---------------------------------------------------------------------------
// gemm_bias: out[M,N] = X[M,K] * Wb[N,K]^T + bias[N]   (bf16 MFMA, fp32 out)
// 128x128 tile, BK=64, 256 threads = 2x2 waves of 64x64.
// Grid dim3(128, 8): x = mtile (so all 8 ntile-blocks of an mtile land on the
// same XCD via linear_id % 8 -> L2 reuse of X), y = ntile.
// Epilogue: per-wave LDS transpose -> float4 stores, 256B contiguous per row.
// ---------------------------------------------------------------------------
__global__ __launch_bounds__(256) void gemm_bias(
        const float* __restrict__ X, const u32* __restrict__ Wb,
        const float* __restrict__ bias, float* __restrict__ out) {
    __shared__ u32 As[128 * LDSW];   // 18 KiB
    __shared__ u32 Bs[128 * LDSW];   // 18 KiB

    const int tid = threadIdx.x;
    const int lane = tid & 63;
    const int wave = tid >> 6;
    const int wr = wave >> 1, wc = wave & 1;
    const int mtile = blockIdx.x;    // 0..127  (fast dim -> XCD = mtile%8)
    const int ntile = blockIdx.y;    // 0..7

    // Staging: thread -> (row = tid>>1, half = tid&1) covering 32 cols each
    const int srow = tid >> 1;
    const int shalf = tid & 1;
    const float* aptr = X + (size_t)(mtile * 128 + srow) * K_DIM + shalf * 32;
    const u32*   bptr = Wb + ((size_t)(ntile * 128 + srow) * K_DIM + shalf * 32) / 2;
    u32* aw = As + srow * LDSW + shalf * 16;
    u32* bw = Bs + srow * LDSW + shalf * 16;

    // Fragment read lanes
    const int fm = lane & 15;
    const int fq = lane >> 4;

    floatx4 acc[4][4] = {};

    float4 av4[8];
    uint4  bv4[4];
    // preload k-tile 0
#pragma unroll
    for (int j = 0; j < 8; ++j) av4[j] = ((const float4*)aptr)[j];
#pragma unroll
    for (int j = 0; j < 4; ++j) bv4[j] = ((const uint4*)bptr)[j];

    for (int kt = 0; kt < K_DIM / 64; ++kt) {
        __syncthreads();   // previous tile's readers done
        // write A (fp32 -> bf16 truncate via v_perm) and B to LDS
#pragma unroll
        for (int j = 0; j < 4; ++j) {
            const u32* f = (const u32*)&av4[j * 2];
            const u32* g = (const u32*)&av4[j * 2 + 1];
            uint4 w;
            w.x = __builtin_amdgcn_perm(f[1], f[0], 0x07060302u);
            w.y = __builtin_amdgcn_perm(f[3], f[2], 0x07060302u);
            w.z = __builtin_amdgcn_perm(g[1], g[0], 0x07060302u);
            w.w = __builtin_amdgcn_perm(g[3], g[2], 0x07060302u);
            *(uint4*)(aw + j * 4) = w;
        }
#pragma unroll
        for (int j = 0; j < 4; ++j) *(uint4*)(bw + j * 4) = bv4[j];
        __syncthreads();

        // prefetch next k-tile while computing this one
        if (kt + 1 < K_DIM / 64) {
            const int k0 = (kt + 1) * 64;
#pragma unroll
            for (int j = 0; j < 8; ++j) av4[j] = ((const float4*)(aptr + k0))[j];
#pragma unroll
            for (int j = 0; j < 4; ++j) bv4[j] = ((const uint4*)(bptr + k0 / 2))[j];
        }

#pragma unroll
        for (int kk = 0; kk < 2; ++kk) {
            short8 afr[4], bfr[4];
#pragma unroll
            for (int mi = 0; mi < 4; ++mi) {
                const int row = wr * 64 + mi * 16 + fm;
                afr[mi] = *(const short8*)(As + row * LDSW + kk * 16 + fq * 4);
            }
#pragma unroll
            for (int ni = 0; ni < 4; ++ni) {
                const int row = wc * 64 + ni * 16 + fm;
                bfr[ni] = *(const short8*)(Bs + row * LDSW + kk * 16 + fq * 4);
            }
#pragma unroll
            for (int mi = 0; mi < 4; ++mi)
#pragma unroll
                for (int ni = 0; ni < 4; ++ni)
                    acc[mi][ni] = __builtin_amdgcn_mfma_f32_16x16x32_bf16(
                        afr[mi], bfr[ni], acc[mi][ni], 0, 0, 0);
        }
    }

    // -----------------------------------------------------------------------
    // Epilogue: D layout col(N)=lane&15, row(M)=(lane>>4)*4+reg.
    // Per wave, per mi: stage 16 rows x 64 cols fp32 in a private LDS slice
    // (stride EPW=68 words), read back row-major, store float4 (256B/row).
    // -----------------------------------------------------------------------
    float bias_r[4];
#pragma unroll
    for (int ni = 0; ni < 4; ++ni)
        bias_r[ni] = bias[ntile * 128 + wc * 64 + ni * 16 + fm];

    float* ep = (float*)As + wave * (16 * EPW);   // 4352 B/wave slice
    const int gm0 = mtile * 128 + wr * 64;
    const int gn0 = ntile * 128 + wc * 64;

#pragma unroll
    for (int mi = 0; mi < 4; ++mi) {
        __syncthreads();   // first iter: protect last k-tile's As readers
#pragma unroll
        for (int ni = 0; ni < 4; ++ni)
#pragma unroll
            for (int reg = 0; reg < 4; ++reg)
                ep[(fq * 4 + reg) * EPW + ni * 16 + fm] = acc[mi][ni][reg] + bias_r[ni];
#pragma unroll
        for (int t = 0; t < 4; ++t) {
            const int lr = t * 4 + (lane >> 4);      // local row 0..15
            const int c4 = lane & 15;                // float4 col
            const float4 v = *(const float4*)(ep + lr * EPW + c4 * 4);
            *(float4*)(out + (size_t)(gm0 + mi * 16 + lr) * N_DIM + gn0 + c4 * 4) = v;
        }
    }
}

// ---------------------------------------------------------------------------
extern "C" void kernel_launch(void* const* d_in, const int* in_sizes, int n_in,
                              void* d_out, int out_size, void* d_ws, size_t ws_size,
                              hipStream_t stream) {
    const float* X   = (const float*)d_in[0];
    const u32*   Yp  = (const u32*)d_in[1];
    const u32*   Zp  = (const u32*)d_in[2];
    const int*   Ys  = (const int*)d_in[3];
    const int*   Zs  = (const int*)d_in[4];
    const float* pa  = (const float*)d_in[5];
    const float* pb  = (const float*)d_in[6];
    const float* pc  = (const float*)d_in[7];
    const float* pd  = (const float*)d_in[8];
    const float* bias = (const float*)d_in[9];
    float* out = (float*)d_out;

    __hip_bfloat16* Wb = (__hip_bfloat16*)d_ws;   // 2 MiB

    build_w<<<256, 256, 0, stream>>>(Yp, Zp, Ys, Zs, pa, pb, pc, pd, Wb);
    gemm_bias<<<dim3(128, 8), 256, 0, stream>>>(X, (const u32*)Wb, bias, out);
}

// Round 3
// 236.735 us; speedup vs baseline: 1.2953x; 1.2084x over previous
//
#include <hip/hip_runtime.h>
#include <hip/hip_bf16.h>
#include <stdint.h>

typedef unsigned int u32;
typedef __attribute__((ext_vector_type(8))) short short8;   // 8 bf16 = 4 VGPRs (MFMA A/B frag)
typedef __attribute__((ext_vector_type(4))) float floatx4;  // MFMA C/D frag

#define N_DIM 1024       // ROW*Y_ROW (output features)
#define K_DIM 1024       // COL*Z_COL (input features)
#define LDSW 36          // main-loop LDS row stride in u32 (64 bf16 = 32 words, +4 pad)
#define EPW  68          // epilogue LDS row stride in words (64 fp32 + 4 pad)

__device__ __forceinline__ u32 pack4(uint4 v) {
    return (v.x & 0xffu) | ((v.y & 0xffu) << 8) | ((v.z & 0xffu) << 16) | (v.w << 24);
}

// ---------------------------------------------------------------------------
// build_w: W[m,k] (bf16, row-major [N_DIM][K_DIM], m=r*128+y, k=c*128+z)
//   = d + sum_bit( a*popcnt(Y&Z) + b*Ysum + c*Zsum )
// Uniform runtime detection of uint8 vs int32-widened packed inputs.
// Grid: 256 blocks = (r,c) x z-quarter, 256 threads.
// ---------------------------------------------------------------------------
__global__ __launch_bounds__(256) void build_w(
        const u32* __restrict__ yp, const u32* __restrict__ zp,
        const int* __restrict__ ysum, const int* __restrict__ zsum,
        const float* __restrict__ pa, const float* __restrict__ pb,
        const float* __restrict__ pc, const float* __restrict__ pd,
        __hip_bfloat16* __restrict__ Wb) {
    __shared__ u32 sY[4096];   // [bit][y][t] words (16 KiB)
    __shared__ u32 sZ[1024];   // [bit][zl][t] words (4 KiB)
    __shared__ int sYs[512];
    __shared__ int sZs[128];

    const int tid = threadIdx.x;
    const int rc = blockIdx.x >> 2;
    const int zq = blockIdx.x & 3;
    const int r = rc >> 3, c = rc & 7;
    const int z0 = zq * 32;

    // uniform mode detect (32 logical bytes vs Y_sum[0])
    const uint4 d0 = ((const uint4*)yp)[0], d1 = ((const uint4*)yp)[1];
    const int sdet = __popc(d0.x) + __popc(d0.y) + __popc(d0.z) + __popc(d0.w)
                   + __popc(d1.x) + __popc(d1.y) + __popc(d1.z) + __popc(d1.w);
    const bool widened = (sdet != ysum[0]);

    if (!widened) {
#pragma unroll
        for (int j = 0; j < 4; ++j) {
            const int chunk = tid + j * 256;
            const int f = chunk * 4;                    // logical word id in block
            const int bit = f >> 10, rem = f & 1023;
            const u32 gw = (u32)((bit * 64 + r * 8 + c) * 1024 + rem);
            ((uint4*)sY)[chunk] = *(const uint4*)(yp + gw);
        }
        {
            const int f = tid * 4;
            const int bit = f >> 8;
            const u32 gw = (u32)((bit * 64 + r * 8 + c) * 1024 + z0 * 8 + (f & 255));
            ((uint4*)sZ)[tid] = *(const uint4*)(zp + gw);
        }
    } else {
#pragma unroll
        for (int j = 0; j < 4; ++j) {
            const int chunk = tid + j * 256;
            const int f = chunk * 4;
            const int bit = f >> 10, rem = f & 1023;
            const u32 gw = (u32)((bit * 64 + r * 8 + c) * 1024 + rem);
            uint4 o;
            o.x = pack4(((const uint4*)yp)[gw + 0]);
            o.y = pack4(((const uint4*)yp)[gw + 1]);
            o.z = pack4(((const uint4*)yp)[gw + 2]);
            o.w = pack4(((const uint4*)yp)[gw + 3]);
            ((uint4*)sY)[chunk] = o;
        }
        {
            const int f = tid * 4;
            const int bit = f >> 8;
            const u32 gw = (u32)((bit * 64 + r * 8 + c) * 1024 + z0 * 8 + (f & 255));
            uint4 o;
            o.x = pack4(((const uint4*)zp)[gw + 0]);
            o.y = pack4(((const uint4*)zp)[gw + 1]);
            o.z = pack4(((const uint4*)zp)[gw + 2]);
            o.w = pack4(((const uint4*)zp)[gw + 3]);
            ((uint4*)sZ)[tid] = o;
        }
    }
    for (int j = tid; j < 512; j += 256) {
        const int bit = j >> 7, y = j & 127;
        sYs[j] = ysum[((bit * 8 + r) * 8 + c) * 128 + y];
    }
    if (tid < 128) {
        const int bit = tid >> 5, zl = tid & 31;
        sZs[tid] = zsum[((bit * 8 + r) * 8 + c) * 128 + z0 + zl];
    }
    __syncthreads();

    float av[4], bv[4], cv[4];
#pragma unroll
    for (int bit = 0; bit < 4; ++bit) { av[bit] = pa[bit]; bv[bit] = pb[bit]; cv[bit] = pc[bit]; }
    const float dv = pd[0];

    const int y = tid & 127;
    const int zh = tid >> 7;       // 0/1 -> 16 z each

    u32 yw[4][8];
    float base = dv;
#pragma unroll
    for (int bit = 0; bit < 4; ++bit) {
        const uint4 q0 = ((const uint4*)sY)[bit * 256 + y * 2];
        const uint4 q1 = ((const uint4*)sY)[bit * 256 + y * 2 + 1];
        yw[bit][0] = q0.x; yw[bit][1] = q0.y; yw[bit][2] = q0.z; yw[bit][3] = q0.w;
        yw[bit][4] = q1.x; yw[bit][5] = q1.y; yw[bit][6] = q1.z; yw[bit][7] = q1.w;
        base += bv[bit] * (float)sYs[bit * 128 + y];
    }

    const int m = r * 128 + y;
#pragma unroll
    for (int zl2 = 0; zl2 < 16; ++zl2) {
        const int zl = zh * 16 + zl2;
        float wv = base;
#pragma unroll
        for (int bit = 0; bit < 4; ++bit) {
            const uint4 zw0 = ((const uint4*)sZ)[bit * 64 + zl * 2];
            const uint4 zw1 = ((const uint4*)sZ)[bit * 64 + zl * 2 + 1];
            int p = 0;
            p += __popc(yw[bit][0] & zw0.x);
            p += __popc(yw[bit][1] & zw0.y);
            p += __popc(yw[bit][2] & zw0.z);
            p += __popc(yw[bit][3] & zw0.w);
            p += __popc(yw[bit][4] & zw1.x);
            p += __popc(yw[bit][5] & zw1.y);
            p += __popc(yw[bit][6] & zw1.z);
            p += __popc(yw[bit][7] & zw1.w);
            wv += av[bit] * (float)p + cv[bit] * (float)sZs[bit * 32 + zl];
        }
        const int k = c * 128 + z0 + zl;
        Wb[(size_t)m * K_DIM + k] = __float2bfloat16(wv);
    }
}

// ---------------------------------------------------------------------------
// gemm_bias: out[M,N] = X[M,K] * Wb[N,K]^T + bias[N]   (bf16 MFMA, fp32 out)
// 128x128 tile, BK=64, 256 threads = 2x2 waves of 64x64.
// Grid dim3(128, 8): x = mtile -> XCD = mtile%8 -> all ntiles of one mtile
// share an XCD's L2 for X.
// Staging is lane-contiguous: instruction j covers flat chunk f = j*256+tid,
// so a wave's 64 lanes read 1 KiB contiguous (16 fully-used 64B lines).
// ---------------------------------------------------------------------------
__global__ __launch_bounds__(256) void gemm_bias(
        const float* __restrict__ X, const u32* __restrict__ Wb,
        const float* __restrict__ bias, float* __restrict__ out) {
    __shared__ u32 As[128 * LDSW];   // 18 KiB
    __shared__ u32 Bs[128 * LDSW];   // 18 KiB

    const int tid = threadIdx.x;
    const int lane = tid & 63;
    const int wave = tid >> 6;
    const int wr = wave >> 1, wc = wave & 1;
    const int mtile = blockIdx.x;    // 0..127  (fast dim -> XCD = mtile%8)
    const int ntile = blockIdx.y;    // 0..7

    // A: 128 rows x 64 fp32 per k-tile = 2048 float4; 16 float4 per row.
    //    instr j: thread reads float4 #(j*256+tid) -> row j*16 + (tid>>4).
    const int ar = tid >> 4, ac = tid & 15;
    // B: 128 rows x 64 bf16 = 1024 uint4; 8 uint4 per row.
    const int br = tid >> 3, bc = tid & 7;

    const float4* xt = (const float4*)X + (size_t)(mtile * 128) * 256;  // 256 f4/row
    const uint4*  wt = (const uint4*)Wb + (size_t)(ntile * 128) * 128;  // 128 u4/row

    // Fragment read lanes
    const int fm = lane & 15;
    const int fq = lane >> 4;

    floatx4 acc[4][4] = {};

    float4 av4[8];
    uint4  bv4[4];
    // preload k-tile 0
#pragma unroll
    for (int j = 0; j < 8; ++j) av4[j] = xt[(size_t)(j * 16 + ar) * 256 + ac];
#pragma unroll
    for (int j = 0; j < 4; ++j) bv4[j] = wt[(size_t)(j * 32 + br) * 128 + bc];

    for (int kt = 0; kt < K_DIM / 64; ++kt) {
        __syncthreads();   // previous tile's readers done
        // A: fp32 -> bf16 truncate via v_perm, ds_write_b64 per float4
#pragma unroll
        for (int j = 0; j < 8; ++j) {
            const u32* f = (const u32*)&av4[j];
            uint2 w;
            w.x = __builtin_amdgcn_perm(f[1], f[0], 0x07060302u);
            w.y = __builtin_amdgcn_perm(f[3], f[2], 0x07060302u);
            *(uint2*)(As + (j * 16 + ar) * LDSW + ac * 2) = w;
        }
#pragma unroll
        for (int j = 0; j < 4; ++j)
            *(uint4*)(Bs + (j * 32 + br) * LDSW + bc * 4) = bv4[j];
        __syncthreads();

        // prefetch next k-tile while computing this one
        if (kt + 1 < K_DIM / 64) {
            const int ka = (kt + 1) * 16;   // float4 offset within row
            const int kb = (kt + 1) * 8;    // uint4 offset within row
#pragma unroll
            for (int j = 0; j < 8; ++j) av4[j] = xt[(size_t)(j * 16 + ar) * 256 + ka + ac];
#pragma unroll
            for (int j = 0; j < 4; ++j) bv4[j] = wt[(size_t)(j * 32 + br) * 128 + kb + bc];
        }

#pragma unroll
        for (int kk = 0; kk < 2; ++kk) {
            short8 afr[4], bfr[4];
#pragma unroll
            for (int mi = 0; mi < 4; ++mi) {
                const int row = wr * 64 + mi * 16 + fm;
                afr[mi] = *(const short8*)(As + row * LDSW + kk * 16 + fq * 4);
            }
#pragma unroll
            for (int ni = 0; ni < 4; ++ni) {
                const int row = wc * 64 + ni * 16 + fm;
                bfr[ni] = *(const short8*)(Bs + row * LDSW + kk * 16 + fq * 4);
            }
#pragma unroll
            for (int mi = 0; mi < 4; ++mi)
#pragma unroll
                for (int ni = 0; ni < 4; ++ni)
                    acc[mi][ni] = __builtin_amdgcn_mfma_f32_16x16x32_bf16(
                        afr[mi], bfr[ni], acc[mi][ni], 0, 0, 0);
        }
    }

    // -----------------------------------------------------------------------
    // Epilogue: D layout col(N)=lane&15, row(M)=(lane>>4)*4+reg.
    // Per wave (private LDS slice, stride EPW): stage 16x64 fp32, read back
    // row-major, store float4 (256B contiguous per quarter-wave).
    // -----------------------------------------------------------------------
    float bias_r[4];
#pragma unroll
    for (int ni = 0; ni < 4; ++ni)
        bias_r[ni] = bias[ntile * 128 + wc * 64 + ni * 16 + fm];

    float* ep = (float*)As + wave * (16 * EPW);   // 4352 B/wave slice
    const int gm0 = mtile * 128 + wr * 64;
    const int gn0 = ntile * 128 + wc * 64;

    __syncthreads();   // all waves done reading As/Bs as tiles
#pragma unroll
    for (int mi = 0; mi < 4; ++mi) {
#pragma unroll
        for (int ni = 0; ni < 4; ++ni)
#pragma unroll
            for (int reg = 0; reg < 4; ++reg)
                ep[(fq * 4 + reg) * EPW + ni * 16 + fm] = acc[mi][ni][reg] + bias_r[ni];
#pragma unroll
        for (int t = 0; t < 4; ++t) {
            const int lr = t * 4 + fq;               // local row 0..15
            const float4 v = *(const float4*)(ep + lr * EPW + fm * 4);
            *(float4*)(out + (size_t)(gm0 + mi * 16 + lr) * N_DIM + gn0 + fm * 4) = v;
        }
        // wave-private slice: compiler's lgkmcnt ordering protects reuse
    }
}

// ---------------------------------------------------------------------------
extern "C" void kernel_launch(void* const* d_in, const int* in_sizes, int n_in,
                              void* d_out, int out_size, void* d_ws, size_t ws_size,
                              hipStream_t stream) {
    const float* X   = (const float*)d_in[0];
    const u32*   Yp  = (const u32*)d_in[1];
    const u32*   Zp  = (const u32*)d_in[2];
    const int*   Ys  = (const int*)d_in[3];
    const int*   Zs  = (const int*)d_in[4];
    const float* pa  = (const float*)d_in[5];
    const float* pb  = (const float*)d_in[6];
    const float* pc  = (const float*)d_in[7];
    const float* pd  = (const float*)d_in[8];
    const float* bias = (const float*)d_in[9];
    float* out = (float*)d_out;

    __hip_bfloat16* Wb = (__hip_bfloat16*)d_ws;   // 2 MiB

    build_w<<<256, 256, 0, stream>>>(Yp, Zp, Ys, Zs, pa, pb, pc, pd, Wb);
    gemm_bias<<<dim3(128, 8), 256, 0, stream>>>(X, (const u32*)Wb, bias, out);
}

// Round 4
// 171.286 us; speedup vs baseline: 1.7902x; 1.3821x over previous
//
#include <hip/hip_runtime.h>
#include <hip/hip_bf16.h>
#include <stdint.h>

typedef unsigned int u32;
typedef unsigned short u16;
typedef __attribute__((ext_vector_type(8))) short short8;   // 8 bf16 (MFMA A/B frag)
typedef __attribute__((ext_vector_type(4))) float floatx4;  // MFMA C/D frag

#define N_DIM 1024       // ROW*Y_ROW (output features)
#define K_DIM 1024       // COL*Z_COL (input features)
#define M_DIM 16384      // BATCH*SEQ
#define EPW  68          // epilogue LDS row stride in words (64 fp32 + 4 pad)

__device__ __forceinline__ u32 pack4(uint4 v) {
    return (v.x & 0xffu) | ((v.y & 0xffu) << 8) | ((v.z & 0xffu) << 16) | (v.w << 24);
}

__device__ __forceinline__ u16 bf16rne(float f) {
    u32 u = __float_as_uint(f);
    return (u16)((u + 0x7fffu + ((u >> 16) & 1u)) >> 16);
}

// async global->LDS, 16B per lane. LDS dest must be wave-uniform base + lane*16.
__device__ __forceinline__ void load16_lds(const void* g, void* l) {
    __builtin_amdgcn_global_load_lds(
        (const __attribute__((address_space(1))) void*)g,
        (__attribute__((address_space(3))) void*)l, 16, 0, 0);
}

// ---------------------------------------------------------------------------
// build_w: W[n,k] (bf16, row-major [N_DIM][K_DIM], n=r*128+y, k=c*128+z)
//   = d + sum_bit( a*popcnt(Y&Z) + b*Ysum + c*Zsum )
// Uniform runtime detection of uint8 vs int32-widened packed inputs.
// Grid: 256 blocks = (r,c) x z-quarter, 256 threads.
// ---------------------------------------------------------------------------
__global__ __launch_bounds__(256) void build_w(
        const u32* __restrict__ yp, const u32* __restrict__ zp,
        const int* __restrict__ ysum, const int* __restrict__ zsum,
        const float* __restrict__ pa, const float* __restrict__ pb,
        const float* __restrict__ pc, const float* __restrict__ pd,
        __hip_bfloat16* __restrict__ Wb) {
    __shared__ u32 sY[4096];   // [bit][y][t] words (16 KiB)
    __shared__ u32 sZ[1024];   // [bit][zl][t] words (4 KiB)
    __shared__ int sYs[512];
    __shared__ int sZs[128];

    const int tid = threadIdx.x;
    const int rc = blockIdx.x >> 2;
    const int zq = blockIdx.x & 3;
    const int r = rc >> 3, c = rc & 7;
    const int z0 = zq * 32;

    // uniform mode detect (32 logical bytes vs Y_sum[0])
    const uint4 d0 = ((const uint4*)yp)[0], d1 = ((const uint4*)yp)[1];
    const int sdet = __popc(d0.x) + __popc(d0.y) + __popc(d0.z) + __popc(d0.w)
                   + __popc(d1.x) + __popc(d1.y) + __popc(d1.z) + __popc(d1.w);
    const bool widened = (sdet != ysum[0]);

    if (!widened) {
#pragma unroll
        for (int j = 0; j < 4; ++j) {
            const int chunk = tid + j * 256;
            const int f = chunk * 4;                    // logical word id in block
            const int bit = f >> 10, rem = f & 1023;
            const u32 gw = (u32)((bit * 64 + r * 8 + c) * 1024 + rem);
            ((uint4*)sY)[chunk] = *(const uint4*)(yp + gw);
        }
        {
            const int f = tid * 4;
            const int bit = f >> 8;
            const u32 gw = (u32)((bit * 64 + r * 8 + c) * 1024 + z0 * 8 + (f & 255));
            ((uint4*)sZ)[tid] = *(const uint4*)(zp + gw);
        }
    } else {
#pragma unroll
        for (int j = 0; j < 4; ++j) {
            const int chunk = tid + j * 256;
            const int f = chunk * 4;
            const int bit = f >> 10, rem = f & 1023;
            const u32 gw = (u32)((bit * 64 + r * 8 + c) * 1024 + rem);
            uint4 o;
            o.x = pack4(((const uint4*)yp)[gw + 0]);
            o.y = pack4(((const uint4*)yp)[gw + 1]);
            o.z = pack4(((const uint4*)yp)[gw + 2]);
            o.w = pack4(((const uint4*)yp)[gw + 3]);
            ((uint4*)sY)[chunk] = o;
        }
        {
            const int f = tid * 4;
            const int bit = f >> 8;
            const u32 gw = (u32)((bit * 64 + r * 8 + c) * 1024 + z0 * 8 + (f & 255));
            uint4 o;
            o.x = pack4(((const uint4*)zp)[gw + 0]);
            o.y = pack4(((const uint4*)zp)[gw + 1]);
            o.z = pack4(((const uint4*)zp)[gw + 2]);
            o.w = pack4(((const uint4*)zp)[gw + 3]);
            ((uint4*)sZ)[tid] = o;
        }
    }
    for (int j = tid; j < 512; j += 256) {
        const int bit = j >> 7, y = j & 127;
        sYs[j] = ysum[((bit * 8 + r) * 8 + c) * 128 + y];
    }
    if (tid < 128) {
        const int bit = tid >> 5, zl = tid & 31;
        sZs[tid] = zsum[((bit * 8 + r) * 8 + c) * 128 + z0 + zl];
    }
    __syncthreads();

    float av[4], bv[4], cv[4];
#pragma unroll
    for (int bit = 0; bit < 4; ++bit) { av[bit] = pa[bit]; bv[bit] = pb[bit]; cv[bit] = pc[bit]; }
    const float dv = pd[0];

    const int y = tid & 127;
    const int zh = tid >> 7;       // 0/1 -> 16 z each

    u32 yw[4][8];
    float base = dv;
#pragma unroll
    for (int bit = 0; bit < 4; ++bit) {
        const uint4 q0 = ((const uint4*)sY)[bit * 256 + y * 2];
        const uint4 q1 = ((const uint4*)sY)[bit * 256 + y * 2 + 1];
        yw[bit][0] = q0.x; yw[bit][1] = q0.y; yw[bit][2] = q0.z; yw[bit][3] = q0.w;
        yw[bit][4] = q1.x; yw[bit][5] = q1.y; yw[bit][6] = q1.z; yw[bit][7] = q1.w;
        base += bv[bit] * (float)sYs[bit * 128 + y];
    }

    const int m = r * 128 + y;
#pragma unroll
    for (int zl2 = 0; zl2 < 16; ++zl2) {
        const int zl = zh * 16 + zl2;
        float wv = base;
#pragma unroll
        for (int bit = 0; bit < 4; ++bit) {
            const uint4 zw0 = ((const uint4*)sZ)[bit * 64 + zl * 2];
            const uint4 zw1 = ((const uint4*)sZ)[bit * 64 + zl * 2 + 1];
            int p = 0;
            p += __popc(yw[bit][0] & zw0.x);
            p += __popc(yw[bit][1] & zw0.y);
            p += __popc(yw[bit][2] & zw0.z);
            p += __popc(yw[bit][3] & zw0.w);
            p += __popc(yw[bit][4] & zw1.x);
            p += __popc(yw[bit][5] & zw1.y);
            p += __popc(yw[bit][6] & zw1.z);
            p += __popc(yw[bit][7] & zw1.w);
            wv += av[bit] * (float)p + cv[bit] * (float)sZs[bit * 32 + zl];
        }
        const int k = c * 128 + z0 + zl;
        Wb[(size_t)m * K_DIM + k] = __float2bfloat16(wv);
    }
}

// ---------------------------------------------------------------------------
// convert_x: X fp32 [16384][1024] -> bf16 (RNE). 8192 blocks x 256 threads,
// 2 float4 per thread, fully coalesced.
// ---------------------------------------------------------------------------
__global__ __launch_bounds__(256) void convert_x(const float4* __restrict__ X,
                                                 ushort4* __restrict__ Xb) {
    const size_t base = (size_t)blockIdx.x * 512;
    const int tid = threadIdx.x;
    const float4 a = X[base + tid];
    const float4 b = X[base + 256 + tid];
    ushort4 oa, ob;
    oa.x = bf16rne(a.x); oa.y = bf16rne(a.y); oa.z = bf16rne(a.z); oa.w = bf16rne(a.w);
    ob.x = bf16rne(b.x); ob.y = bf16rne(b.y); ob.z = bf16rne(b.z); ob.w = bf16rne(b.w);
    Xb[base + tid] = oa;
    Xb[base + 256 + tid] = ob;
}

// ---------------------------------------------------------------------------
// gemm_bias: out[M,N] = Xb[M,K] * Wb[N,K]^T + bias[N]   (bf16 MFMA, fp32 out)
// Block tile 256(M) x 128(N), BK=64, 512 threads = 8 waves (4 M x 2 N) of
// 64x64. Both tiles staged via global_load_lds (16B/lane), XOR-swizzled LDS
// layout: 16B chunk (row, kc) stored at chunk index row*8 + (kc ^ (row&7)).
// Grid dim3(64, 8): x = mtile -> XCD = mtile%8; the 8 ntile-blocks of one
// mtile are co-resident on the same XCD -> A-tile served from L2.
// ---------------------------------------------------------------------------
__global__ __launch_bounds__(512, 4) void gemm_bias(
        const u16* __restrict__ Xb, const u16* __restrict__ Wb,
        const float* __restrict__ bias, float* __restrict__ out) {
    __shared__ char lds[49152];
    char* As = lds;              // 32 KB: 256 rows x 128 B (swizzled)
    char* Bs = lds + 32768;      // 16 KB: 128 rows x 128 B (swizzled)

    const int tid = threadIdx.x;
    const int lane = tid & 63;
    const int w = tid >> 6;          // wave 0..7
    const int wr = w >> 1;           // 0..3 (M)
    const int wc = w & 1;            // 0..1 (N)
    const int mtile = blockIdx.x;    // 0..63
    const int ntile = blockIdx.y;    // 0..7
    const int m0 = mtile * 256, n0 = ntile * 128;

    // staging lane decomposition: 64 lanes cover 8 rows x 8 chunks
    const int lrow = lane >> 3;                  // 0..7
    const int lkc  = (lane & 7) ^ lrow;          // swizzled source 16B-chunk
    // fragment lanes
    const int fm = lane & 15, fq = lane >> 4;
    const int cx0 = ((0 + fq) ^ (fm & 7)) * 16;  // kk=0 swizzled byte col
    const int cx1 = ((4 + fq) ^ (fm & 7)) * 16;  // kk=1

    floatx4 acc[4][4] = {};

    for (int kt = 0; kt < K_DIM / 64; ++kt) {
        __syncthreads();   // previous tile's readers done
        // A: 2048 chunks (256 rows x 8), 4 instr/thread
#pragma unroll
        for (int j = 0; j < 4; ++j) {
            const int cw = j * 8 + w;                 // chunk-group 0..31
            const int row = cw * 8 + lrow;            // 0..255
            load16_lds(Xb + (size_t)(m0 + row) * K_DIM + kt * 64 + lkc * 8,
                       As + cw * 1024 + lane * 16);
        }
        // B: 1024 chunks (128 rows x 8), 2 instr/thread
#pragma unroll
        for (int j = 0; j < 2; ++j) {
            const int cw = j * 8 + w;                 // 0..15
            const int row = cw * 8 + lrow;            // 0..127
            load16_lds(Wb + (size_t)(n0 + row) * K_DIM + kt * 64 + lkc * 8,
                       Bs + cw * 1024 + lane * 16);
        }
        __syncthreads();   // (compiler emits vmcnt(0) drain before barrier)

#pragma unroll
        for (int kk = 0; kk < 2; ++kk) {
            const int cx = kk ? cx1 : cx0;
            short8 afr[4], bfr[4];
#pragma unroll
            for (int mi = 0; mi < 4; ++mi)
                afr[mi] = *(const short8*)(As + (wr * 64 + mi * 16 + fm) * 128 + cx);
#pragma unroll
            for (int ni = 0; ni < 4; ++ni)
                bfr[ni] = *(const short8*)(Bs + (wc * 64 + ni * 16 + fm) * 128 + cx);
#pragma unroll
            for (int mi = 0; mi < 4; ++mi)
#pragma unroll
                for (int ni = 0; ni < 4; ++ni)
                    acc[mi][ni] = __builtin_amdgcn_mfma_f32_16x16x32_bf16(
                        afr[mi], bfr[ni], acc[mi][ni], 0, 0, 0);
        }
    }

    // -----------------------------------------------------------------------
    // Epilogue: D layout col(N)=lane&15, row(M)=(lane>>4)*4+reg.
    // Per-wave private LDS slice (16 x EPW fp32): transpose to row-major,
    // store float4 (256 B contiguous per 16-lane group).
    // -----------------------------------------------------------------------
    float bias_r[4];
#pragma unroll
    for (int ni = 0; ni < 4; ++ni)
        bias_r[ni] = bias[n0 + wc * 64 + ni * 16 + fm];

    __syncthreads();   // all waves done with As/Bs tiles
    float* ep = (float*)lds + w * (16 * EPW);   // 4352 B per wave, 34.8 KB total
    const int gm0 = m0 + wr * 64;
    const int gn0 = n0 + wc * 64;

#pragma unroll
    for (int mi = 0; mi < 4; ++mi) {
#pragma unroll
        for (int ni = 0; ni < 4; ++ni)
#pragma unroll
            for (int reg = 0; reg < 4; ++reg)
                ep[(fq * 4 + reg) * EPW + ni * 16 + fm] = acc[mi][ni][reg] + bias_r[ni];
#pragma unroll
        for (int t = 0; t < 4; ++t) {
            const int lr = t * 4 + fq;               // local row 0..15
            const float4 v = *(const float4*)(ep + lr * EPW + fm * 4);
            *(float4*)(out + (size_t)(gm0 + mi * 16 + lr) * N_DIM + gn0 + fm * 4) = v;
        }
        // wave-private slice; DS pipe is in-order per wave -> WAR safe
    }
}

// ---------------------------------------------------------------------------
extern "C" void kernel_launch(void* const* d_in, const int* in_sizes, int n_in,
                              void* d_out, int out_size, void* d_ws, size_t ws_size,
                              hipStream_t stream) {
    const float* X   = (const float*)d_in[0];
    const u32*   Yp  = (const u32*)d_in[1];
    const u32*   Zp  = (const u32*)d_in[2];
    const int*   Ys  = (const int*)d_in[3];
    const int*   Zs  = (const int*)d_in[4];
    const float* pa  = (const float*)d_in[5];
    const float* pb  = (const float*)d_in[6];
    const float* pc  = (const float*)d_in[7];
    const float* pd  = (const float*)d_in[8];
    const float* bias = (const float*)d_in[9];
    float* out = (float*)d_out;

    char* ws = (char*)d_ws;
    __hip_bfloat16* Wb = (__hip_bfloat16*)ws;                 // 2 MiB
    u16*            Xb = (u16*)(ws + (2u << 20));             // 32 MiB

    build_w<<<256, 256, 0, stream>>>(Yp, Zp, Ys, Zs, pa, pb, pc, pd, Wb);
    convert_x<<<8192, 256, 0, stream>>>((const float4*)X, (ushort4*)Xb);
    gemm_bias<<<dim3(64, 8), 512, 0, stream>>>(Xb, (const u16*)Wb, bias, out);
}